// Round 4
// baseline (198.365 us; speedup 1.0000x reference)
//
#include <hip/hip_runtime.h>
#include <stdint.h>

typedef _Float16 h8 __attribute__((ext_vector_type(8)));
typedef float f16x __attribute__((ext_vector_type(16)));

#define ALPHA_C 1000.0f
#define EPS_C 1e-6f
#define NPTS 8192
#define BATCH 4
#define TPB 256
#define WAVES 4
#define QPW 32                    // queries per wave (MFMA M)
#define QPB (WAVES * QPW)         // 128 queries per block
#define NQC (NPTS / QPB)          // 64 query chunks
#define SLICES 8
#define CSLICE (NPTS / SLICES)    // 1024 candidates per block
#define TILES (CSLICE / 32)       // 32 MFMA tiles per block
#define NN_BLOCKS (2 * BATCH * NQC * SLICES)  // 4096
#define TOTQ (2 * BATCH * NPTS)   // 65536
#define POST_BLOCKS (TOTQ / TPB)  // 256

// ---------------------------------------------------------------------------
// nn_kernel: S = Q·C^T + bias via mfma_f32_32x32x16_f16 with exact fp16
// hi/lo split (K-slots: qh*ch(3) qh*cl(3) ql*ch(3) ql*cl(3) 1*wh 1*wl).
// Per-wave running argmax over candidate tiles; per-slice winner stored with
// a plain store as key (s_bits<<32 | ~idx)  (~idx => smaller index wins ties).
// Also zero-inits counts/expsum/done (replaces the memset dispatch).
// ---------------------------------------------------------------------------
__global__ __launch_bounds__(TPB) void nn_kernel(
    const float* __restrict__ x, const float* __restrict__ y,
    unsigned long long* __restrict__ bests, unsigned int* __restrict__ counts,
    float* __restrict__ expsum, unsigned int* __restrict__ done) {
  int bid = blockIdx.x;
  int tid = threadIdx.x;

  // fold workspace init into this dispatch (visible to post_kernel at the
  // dispatch boundary; no intra-kernel ordering needed)
  if (bid < TOTQ / TPB) {
    counts[bid * TPB + tid] = 0u;
    expsum[bid * TPB + tid] = 0.0f;
    if (bid == 0 && tid == 0) *done = 0u;
  }

  int slice = bid & (SLICES - 1);
  int qc = (bid >> 3) & (NQC - 1);
  int db = bid >> 9;  // dir*4 + b
  int b = db & (BATCH - 1);
  int dir = db >> 2;

  const float* qp = (dir == 0 ? x : y) + b * NPTS * 3;
  const float* cp = (dir == 0 ? y : x) + b * NPTS * 3;

  // B fragments pre-swizzled to MFMA fragment order: tile t, lane l -> 16B at
  // tileB[t*64 + l]; conflict-free ds_read_b128 in the inner loop.
  __shared__ h8 tileB[TILES * 64];  // 32 KiB

  int cbase = slice * CSLICE;
#pragma unroll
  for (int k2 = 0; k2 < CSLICE / TPB; k2++) {
    int lc = tid + k2 * TPB;  // 0..1023
    int c = cbase + lc;
    float c0 = cp[c * 3 + 0], c1 = cp[c * 3 + 1], c2 = cp[c * 3 + 2];
    _Float16 h0 = (_Float16)c0, h1 = (_Float16)c1, h2 = (_Float16)c2;
    _Float16 l0 = (_Float16)(c0 - (float)h0);
    _Float16 l1 = (_Float16)(c1 - (float)h1);
    _Float16 l2 = (_Float16)(c2 - (float)h2);
    float w = 2.0f - 0.5f * (c0 * c0 + c1 * c1 + c2 * c2);
    _Float16 wh = (_Float16)w;
    _Float16 wl = (_Float16)(w - (float)wh);
    // k0..7  : ch0 ch1 ch2 cl0 cl1 cl2 ch0 ch1
    // k8..15 : ch2 cl0 cl1 cl2 wh  wl  0   0
    h8 b0 = {h0, h1, h2, l0, l1, l2, h0, h1};
    h8 b1 = {h2, l0, l1, l2, wh, wl, (_Float16)0.0f, (_Float16)0.0f};
    int t = lc >> 5, col = lc & 31;
    tileB[t * 64 + col] = b0;
    tileB[t * 64 + 32 + col] = b1;
  }
  __syncthreads();

  int wave = tid >> 6, lane = tid & 63;
  int row = lane & 31, khalf = lane >> 5;
  int qwbase = qc * QPB + wave * QPW;
  int q = qwbase + row;
  float q0 = qp[q * 3 + 0], q1 = qp[q * 3 + 1], q2 = qp[q * 3 + 2];
  _Float16 a0 = (_Float16)q0, a1 = (_Float16)q1, a2 = (_Float16)q2;
  _Float16 e0 = (_Float16)(q0 - (float)a0);
  _Float16 e1 = (_Float16)(q1 - (float)a1);
  _Float16 e2 = (_Float16)(q2 - (float)a2);
  h8 af;
  if (khalf == 0) {
    // k0..7 : qh0 qh1 qh2 qh0 qh1 qh2 ql0 ql1
    af = (h8){a0, a1, a2, a0, a1, a2, e0, e1};
  } else {
    // k8..15: ql2 ql0 ql1 ql2 1 1 0 0
    af = (h8){e2, e0, e1, e2, (_Float16)1.0f, (_Float16)1.0f, (_Float16)0.0f,
              (_Float16)0.0f};
  }

  float best[16];
  int bidx[16];
#pragma unroll
  for (int r = 0; r < 16; r++) {
    best[r] = 0.0f;  // s >= 0.5 always
    bidx[r] = 0;
  }

  const h8* bp = tileB + lane;
  const f16x zacc = {};
#pragma unroll 2
  for (int t = 0; t < TILES; t++) {
    h8 bf = bp[t * 64];
    f16x acc = __builtin_amdgcn_mfma_f32_32x32x16_f16(af, bf, zacc, 0, 0, 0);
    int cand = cbase + t * 32 + row;
#pragma unroll
    for (int r = 0; r < 16; r++) {
      bool gt = acc[r] > best[r];  // strict > keeps earliest tile (smaller idx)
      best[r] = gt ? acc[r] : best[r];
      bidx[r] = gt ? cand : bidx[r];
    }
  }

  // cross-lane argmax per row (cols live on 32 lanes of each half), then one
  // plain store per (slice, query)
  unsigned long long* ob = bests + ((size_t)slice * 8 + db) * NPTS;
#pragma unroll
  for (int r = 0; r < 16; r++) {
    unsigned long long key =
        ((unsigned long long)__float_as_uint(best[r]) << 32) |
        (unsigned long long)(unsigned int)(~bidx[r]);
#pragma unroll
    for (int m = 1; m < 32; m <<= 1) {
      unsigned long long o = __shfl_xor(key, m, 64);
      key = (o > key) ? o : key;
    }
    if (row == 0) {
      int rr = (r & 3) + 8 * (r >> 2) + 4 * khalf;  // C/D row mapping
      ob[qwbase + rr] = key;
    }
  }
}

// ---------------------------------------------------------------------------
// post_kernel: merge 8 slice winners per query, exact d (reference fp order),
// scatter exp/count atomics; done-counter lets the last block reduce
// sum_c expsum[c]/(cnt[c]+eps) and write out = 1 - total/65536.
// ---------------------------------------------------------------------------
__global__ __launch_bounds__(TPB) void post_kernel(
    const float* __restrict__ x, const float* __restrict__ y,
    const unsigned long long* __restrict__ bests,
    unsigned int* __restrict__ counts, float* __restrict__ expsum,
    unsigned int* __restrict__ done, float* __restrict__ out) {
  int i = blockIdx.x * TPB + threadIdx.x;
  int q = i & (NPTS - 1);
  int db = i >> 13;
  int b = db & (BATCH - 1);
  int dir = db >> 2;

  unsigned long long key = 0ull;
#pragma unroll
  for (int s = 0; s < SLICES; s++) {
    unsigned long long k2 = bests[((size_t)s * 8 + db) * NPTS + q];
    key = (k2 > key) ? k2 : key;
  }
  unsigned int idx = ~(unsigned int)(key & 0xFFFFFFFFull);

  const float* qp = (dir == 0 ? x : y) + b * NPTS * 3;
  const float* cp = (dir == 0 ? y : x) + b * NPTS * 3;
  float axv = qp[q * 3 + 0], ayv = qp[q * 3 + 1], azv = qp[q * 3 + 2];
  float bxv = cp[idx * 3 + 0], byv = cp[idx * 3 + 1], bzv = cp[idx * 3 + 2];
  float xx = axv * axv + ayv * ayv + azv * azv;
  float yy = bxv * bxv + byv * byv + bzv * bzv;
  float xy = axv * bxv + ayv * byv + azv * bzv;
  float d = xx - 2.0f * xy + yy;

  int base = db << 13;
  atomicAdd(expsum + base + idx, expf(-d * ALPHA_C));
  atomicAdd(counts + base + idx, 1u);

  __shared__ bool amLast;
  __syncthreads();
  if (threadIdx.x == 0) {
    __threadfence();
    unsigned int t = atomicAdd(done, 1u);
    amLast = (t == POST_BLOCKS - 1);
  }
  __syncthreads();

  if (amLast) {
    __threadfence();  // acquire side
    float v = 0.0f;
    for (int j = threadIdx.x; j < TOTQ; j += TPB) {
      float e = __hip_atomic_load(&expsum[j], __ATOMIC_RELAXED,
                                  __HIP_MEMORY_SCOPE_AGENT);
      unsigned int c = __hip_atomic_load(&counts[j], __ATOMIC_RELAXED,
                                         __HIP_MEMORY_SCOPE_AGENT);
      v += e / ((float)c + EPS_C);
    }
#pragma unroll
    for (int o = 32; o > 0; o >>= 1) v += __shfl_down(v, o, 64);
    __shared__ float wsum[WAVES];
    if ((threadIdx.x & 63) == 0) wsum[threadIdx.x >> 6] = v;
    __syncthreads();
    if (threadIdx.x == 0) {
      float total = wsum[0] + wsum[1] + wsum[2] + wsum[3];
      out[0] = 1.0f - total * (1.0f / (float)TOTQ);
    }
  }
}

extern "C" void kernel_launch(void* const* d_in, const int* in_sizes, int n_in,
                              void* d_out, int out_size, void* d_ws,
                              size_t ws_size, hipStream_t stream) {
  const float* x = (const float*)d_in[0];
  const float* y = (const float*)d_in[1];
  float* out = (float*)d_out;

  // ws: bests [SLICES][8][NPTS] u64 (4 MiB) | counts u32 | expsum f32 | done
  char* p = (char*)d_ws;
  unsigned long long* bests = (unsigned long long*)p;
  unsigned int* counts =
      (unsigned int*)(p + (size_t)SLICES * 8 * NPTS * 8);
  float* expsum = (float*)(p + (size_t)SLICES * 8 * NPTS * 8 + (size_t)TOTQ * 4);
  unsigned int* done =
      (unsigned int*)(p + (size_t)SLICES * 8 * NPTS * 8 + (size_t)TOTQ * 8);

  nn_kernel<<<NN_BLOCKS, TPB, 0, stream>>>(x, y, bests, counts, expsum, done);
  post_kernel<<<POST_BLOCKS, TPB, 0, stream>>>(x, y, bests, counts, expsum,
                                               done, out);
}

// Round 5
// 129.019 us; speedup vs baseline: 1.5375x; 1.5375x over previous
//
#include <hip/hip_runtime.h>
#include <stdint.h>

typedef _Float16 h8 __attribute__((ext_vector_type(8)));
typedef float f16x __attribute__((ext_vector_type(16)));

#define ALPHA_C 1000.0f
#define EPS_C 1e-6f
#define NPTS 8192
#define BATCH 4
#define TPB 256
#define WAVES 4
#define QPW 32                    // queries per wave (MFMA M)
#define QPB (WAVES * QPW)         // 128 queries per block
#define NQC (NPTS / QPB)          // 64 query chunks
#define SLICES 8
#define CSLICE (NPTS / SLICES)    // 1024 candidates per block
#define TILES (CSLICE / 32)       // 32 MFMA tiles per block
#define NN_BLOCKS (2 * BATCH * NQC * SLICES)  // 4096
#define TOTQ (2 * BATCH * NPTS)   // 65536
#define POST_BLOCKS (TOTQ / TPB)  // 256
#define FIN_BLOCKS (TOTQ / (TPB * 4))  // 64

// ---------------------------------------------------------------------------
// nn_kernel: S = Q·C^T + bias via mfma_f32_32x32x16_f16 with exact fp16
// hi/lo split (K-slots: qh*ch(3) qh*cl(3) ql*ch(3) ql*cl(3) 1*wh 1*wl).
// Per-wave running argmax over candidate tiles; per-slice winner stored with
// a plain store as key (s_bits<<32 | ~idx)  (~idx => smaller index wins ties).
// Also zero-inits counts/expsum and seeds out[0]=1.0 (final subtracts).
// ---------------------------------------------------------------------------
__global__ __launch_bounds__(TPB) void nn_kernel(
    const float* __restrict__ x, const float* __restrict__ y,
    unsigned long long* __restrict__ bests, unsigned int* __restrict__ counts,
    float* __restrict__ expsum, float* __restrict__ out) {
  int bid = blockIdx.x;
  int tid = threadIdx.x;

  // fold workspace init into this dispatch (visible to later dispatches at
  // the dispatch boundary)
  if (bid < TOTQ / TPB) {
    counts[bid * TPB + tid] = 0u;
    expsum[bid * TPB + tid] = 0.0f;
    if (bid == 0 && tid == 0) out[0] = 1.0f;
  }

  int slice = bid & (SLICES - 1);
  int qc = (bid >> 3) & (NQC - 1);
  int db = bid >> 9;  // dir*4 + b
  int b = db & (BATCH - 1);
  int dir = db >> 2;

  const float* qp = (dir == 0 ? x : y) + b * NPTS * 3;
  const float* cp = (dir == 0 ? y : x) + b * NPTS * 3;

  // B fragments pre-swizzled to MFMA fragment order: tile t, lane l -> 16B at
  // tileB[t*64 + l]; conflict-free ds_read_b128 in the inner loop.
  __shared__ h8 tileB[TILES * 64];  // 32 KiB

  int cbase = slice * CSLICE;
#pragma unroll
  for (int k2 = 0; k2 < CSLICE / TPB; k2++) {
    int lc = tid + k2 * TPB;  // 0..1023
    int c = cbase + lc;
    float c0 = cp[c * 3 + 0], c1 = cp[c * 3 + 1], c2 = cp[c * 3 + 2];
    _Float16 h0 = (_Float16)c0, h1 = (_Float16)c1, h2 = (_Float16)c2;
    _Float16 l0 = (_Float16)(c0 - (float)h0);
    _Float16 l1 = (_Float16)(c1 - (float)h1);
    _Float16 l2 = (_Float16)(c2 - (float)h2);
    float w = 2.0f - 0.5f * (c0 * c0 + c1 * c1 + c2 * c2);
    _Float16 wh = (_Float16)w;
    _Float16 wl = (_Float16)(w - (float)wh);
    // k0..7  : ch0 ch1 ch2 cl0 cl1 cl2 ch0 ch1
    // k8..15 : ch2 cl0 cl1 cl2 wh  wl  0   0
    h8 b0 = {h0, h1, h2, l0, l1, l2, h0, h1};
    h8 b1 = {h2, l0, l1, l2, wh, wl, (_Float16)0.0f, (_Float16)0.0f};
    int t = lc >> 5, col = lc & 31;
    tileB[t * 64 + col] = b0;
    tileB[t * 64 + 32 + col] = b1;
  }
  __syncthreads();

  int wave = tid >> 6, lane = tid & 63;
  int row = lane & 31, khalf = lane >> 5;
  int qwbase = qc * QPB + wave * QPW;
  int q = qwbase + row;
  float q0 = qp[q * 3 + 0], q1 = qp[q * 3 + 1], q2 = qp[q * 3 + 2];
  _Float16 a0 = (_Float16)q0, a1 = (_Float16)q1, a2 = (_Float16)q2;
  _Float16 e0 = (_Float16)(q0 - (float)a0);
  _Float16 e1 = (_Float16)(q1 - (float)a1);
  _Float16 e2 = (_Float16)(q2 - (float)a2);
  h8 af;
  if (khalf == 0) {
    // k0..7 : qh0 qh1 qh2 qh0 qh1 qh2 ql0 ql1
    af = (h8){a0, a1, a2, a0, a1, a2, e0, e1};
  } else {
    // k8..15: ql2 ql0 ql1 ql2 1 1 0 0
    af = (h8){e2, e0, e1, e2, (_Float16)1.0f, (_Float16)1.0f, (_Float16)0.0f,
              (_Float16)0.0f};
  }

  float best[16];
  int bidx[16];
#pragma unroll
  for (int r = 0; r < 16; r++) {
    best[r] = 0.0f;  // s >= 0.5 always
    bidx[r] = 0;
  }

  const h8* bp = tileB + lane;
  const f16x zacc = {};
#pragma unroll 2
  for (int t = 0; t < TILES; t++) {
    h8 bf = bp[t * 64];
    f16x acc = __builtin_amdgcn_mfma_f32_32x32x16_f16(af, bf, zacc, 0, 0, 0);
    int cand = cbase + t * 32 + row;
#pragma unroll
    for (int r = 0; r < 16; r++) {
      bool gt = acc[r] > best[r];  // strict > keeps earliest tile (smaller idx)
      best[r] = gt ? acc[r] : best[r];
      bidx[r] = gt ? cand : bidx[r];
    }
  }

  // cross-lane argmax per row (cols live on 32 lanes of each half), then one
  // plain store per (slice, query)
  unsigned long long* ob = bests + ((size_t)slice * 8 + db) * NPTS;
#pragma unroll
  for (int r = 0; r < 16; r++) {
    unsigned long long key =
        ((unsigned long long)__float_as_uint(best[r]) << 32) |
        (unsigned long long)(unsigned int)(~bidx[r]);
#pragma unroll
    for (int m = 1; m < 32; m <<= 1) {
      unsigned long long o = __shfl_xor(key, m, 64);
      key = (o > key) ? o : key;
    }
    if (row == 0) {
      int rr = (r & 3) + 8 * (r >> 2) + 4 * khalf;  // C/D row mapping
      ob[qwbase + rr] = key;
    }
  }
}

// ---------------------------------------------------------------------------
// post_kernel: merge 8 slice winners per query, exact d (reference fp order),
// scatter exp(-alpha*d) and count atomics. No tail reduction here.
// ---------------------------------------------------------------------------
__global__ __launch_bounds__(TPB) void post_kernel(
    const float* __restrict__ x, const float* __restrict__ y,
    const unsigned long long* __restrict__ bests,
    unsigned int* __restrict__ counts, float* __restrict__ expsum) {
  int i = blockIdx.x * TPB + threadIdx.x;
  int q = i & (NPTS - 1);
  int db = i >> 13;
  int b = db & (BATCH - 1);
  int dir = db >> 2;

  unsigned long long key = 0ull;
#pragma unroll
  for (int s = 0; s < SLICES; s++) {
    unsigned long long k2 = bests[((size_t)s * 8 + db) * NPTS + q];
    key = (k2 > key) ? k2 : key;
  }
  unsigned int idx = ~(unsigned int)(key & 0xFFFFFFFFull);

  const float* qp = (dir == 0 ? x : y) + b * NPTS * 3;
  const float* cp = (dir == 0 ? y : x) + b * NPTS * 3;
  float axv = qp[q * 3 + 0], ayv = qp[q * 3 + 1], azv = qp[q * 3 + 2];
  float bxv = cp[idx * 3 + 0], byv = cp[idx * 3 + 1], bzv = cp[idx * 3 + 2];
  float xx = axv * axv + ayv * ayv + azv * azv;
  float yy = bxv * bxv + byv * byv + bzv * bzv;
  float xy = axv * bxv + ayv * byv + azv * bzv;
  float d = xx - 2.0f * xy + yy;

  int base = db << 13;
  atomicAdd(expsum + base + idx, expf(-d * ALPHA_C));
  atomicAdd(counts + base + idx, 1u);
}

// ---------------------------------------------------------------------------
// final_kernel: total = sum_c expsum[c]/(cnt[c]+eps) with plain coalesced
// vector loads (values final at dispatch boundary; kernel-start acquire
// invalidates L1). out was seeded to 1.0; subtract block partials.
// ---------------------------------------------------------------------------
__global__ __launch_bounds__(TPB) void final_kernel(
    const unsigned int* __restrict__ counts, const float* __restrict__ expsum,
    float* __restrict__ out) {
  int j = (blockIdx.x * TPB + threadIdx.x) * 4;
  float4 e = *(const float4*)(expsum + j);
  uint4 c = *(const uint4*)(counts + j);
  float v = e.x / ((float)c.x + EPS_C) + e.y / ((float)c.y + EPS_C) +
            e.z / ((float)c.z + EPS_C) + e.w / ((float)c.w + EPS_C);
#pragma unroll
  for (int o = 32; o > 0; o >>= 1) v += __shfl_down(v, o, 64);
  __shared__ float wsum[WAVES];
  if ((threadIdx.x & 63) == 0) wsum[threadIdx.x >> 6] = v;
  __syncthreads();
  if (threadIdx.x == 0) {
    float t = wsum[0] + wsum[1] + wsum[2] + wsum[3];
    atomicAdd(out, -t * (1.0f / (float)TOTQ));
  }
}

extern "C" void kernel_launch(void* const* d_in, const int* in_sizes, int n_in,
                              void* d_out, int out_size, void* d_ws,
                              size_t ws_size, hipStream_t stream) {
  const float* x = (const float*)d_in[0];
  const float* y = (const float*)d_in[1];
  float* out = (float*)d_out;

  // ws: bests [SLICES][8][NPTS] u64 (4 MiB) | counts u32 | expsum f32
  char* p = (char*)d_ws;
  unsigned long long* bests = (unsigned long long*)p;
  unsigned int* counts = (unsigned int*)(p + (size_t)SLICES * 8 * NPTS * 8);
  float* expsum =
      (float*)(p + (size_t)SLICES * 8 * NPTS * 8 + (size_t)TOTQ * 4);

  nn_kernel<<<NN_BLOCKS, TPB, 0, stream>>>(x, y, bests, counts, expsum, out);
  post_kernel<<<POST_BLOCKS, TPB, 0, stream>>>(x, y, bests, counts, expsum);
  final_kernel<<<FIN_BLOCKS, TPB, 0, stream>>>(counts, expsum, out);
}